// Round 12
// baseline (167.599 us; speedup 1.0000x reference)
//
#include <hip/hip_runtime.h>
#include <hip/hip_fp16.h>

// GCN 2-layer + classifier, fp32 math, fp16 message buffers.
// out[d] = inv[d]*(Ps[d] + sum_{e->d} Ps[src]) + b with Ps = inv*h (weight-free agg).
// Launches:
//   L1 k_hist_gemm: per-tile bucket histogram || W1-GEMM -> P1 UNSCALED fp16
//   L2 k_scanH:  per-bucket exclusive scan of H across tiles + btot
//   L3 k_scatA:  scatter {dloc,src} recs into bucket regions (LDS cursors, zero
//                global atomics; R3: coarse global cursors serialize, R6: random
//                scatter = 55MB dirty-line episodes)
//   L4 k_binB:   per-bucket node hist+scan -> row_ptr/inv; coalesced u16 col;
//                P1 *= inv in-place; DEGREE-SORTED perm (counting sort per bucket)
//                so each agg quad gets ~equal-degree nodes (dmax ~= deg, kills the
//                ~40% masked-gather waste of max-of-4 Poisson)
//   L5 k_aggF1:  agg layer1 via perm (gather P1, masked unroll x8) + fused W2 GEMM
//   L6 k_aggF2:  agg layer2 via perm + fused classifier (transposed LDS Wc; R5)
// fp16 message buffers halve gather fetch (R8: 86->45MB, 8-XCD L2 replication).
// R10 lesson: hipLaunchCooperativeKernel no-ops under graph capture.
// n=50000 (<65536 for u16 col/perm), E=800000.

#define FDIM 64
#define NCLS 16
#define TILE 2048
#define COLCAP 8192

// ---- L1: histogram tiles || W1-GEMM (unscaled fp16 out) ----
__global__ __launch_bounds__(256) void k_hist_gemm(const int* __restrict__ dst, int E, int nblk,
                                                   int* __restrict__ H,
                                                   const float* __restrict__ X,
                                                   const float* __restrict__ W,
                                                   __half* __restrict__ Yh, int n) {
    __shared__ float Ws[FDIM * FDIM];
    int t = threadIdx.x, bid = blockIdx.x;
    if (bid < nblk) {
        int* h = (int*)Ws;
        h[t] = 0;
        __syncthreads();
        int i0 = bid * TILE;
#pragma unroll
        for (int k = 0; k < TILE / 256; ++k) {
            int i = i0 + k * 256 + t;
            if (i < E) atomicAdd(&h[dst[i] >> 8], 1);
        }
        __syncthreads();
        H[bid * 256 + t] = h[t];
        return;
    }
    int g = bid - nblk;
    for (int i = t; i < FDIM * FDIM; i += 256) Ws[i] = W[i];
    __syncthreads();
    int idx = g * 256 + t;
    int row = idx >> 2;
    int cgp = (idx & 3) * 16;
    if (row >= n) return;
    const float4* xr = (const float4*)(X + (size_t)row * FDIM);
    float4 xv[16];
#pragma unroll
    for (int i = 0; i < 16; ++i) xv[i] = xr[i];
    float acc[16];
#pragma unroll
    for (int c = 0; c < 16; ++c) acc[c] = 0.f;
#pragma unroll
    for (int i = 0; i < 16; ++i) {
        float xs[4] = {xv[i].x, xv[i].y, xv[i].z, xv[i].w};
#pragma unroll
        for (int j = 0; j < 4; ++j) {
            float xk = xs[j];
            const float* wr = &Ws[(i * 4 + j) * FDIM + cgp];
#pragma unroll
            for (int c = 0; c < 16; ++c) acc[c] += xk * wr[c];
        }
    }
    unsigned u[8];
#pragma unroll
    for (int i = 0; i < 8; ++i) {
        __half2 hp = __floats2half2_rn(acc[2 * i], acc[2 * i + 1]);
        u[i] = *(unsigned*)&hp;
    }
    uint4* yo = (uint4*)(Yh + (size_t)row * FDIM + cgp);
    yo[0] = make_uint4(u[0], u[1], u[2], u[3]);
    yo[1] = make_uint4(u[4], u[5], u[6], u[7]);
}

// ---- L2: per-bucket exclusive scan across tiles ----
__global__ __launch_bounds__(512) void k_scanH(int* __restrict__ H, int nblk, int* __restrict__ btot) {
    __shared__ int s[512];
    int t = threadIdx.x, b = blockIdx.x;
    int v = (t < nblk) ? H[t * 256 + b] : 0;
    s[t] = v;
    __syncthreads();
    for (int off = 1; off < 512; off <<= 1) {
        int add = (t >= off) ? s[t - off] : 0;
        __syncthreads();
        s[t] += add;
        __syncthreads();
    }
    if (t < nblk) H[t * 256 + b] = s[t] - v;  // exclusive within bucket
    if (t == 511) btot[b] = s[511];
}

// ---- L3: scatter packed records into bucket regions ----
__global__ __launch_bounds__(256) void k_scatA(const int* __restrict__ src, const int* __restrict__ dst,
                                               int E, const int* __restrict__ H,
                                               const int* __restrict__ btot, int nb,
                                               unsigned* __restrict__ tmp) {
    __shared__ int s[256];
    __shared__ int Hb[256];
    __shared__ int c2[256];
    int t = threadIdx.x, blk = blockIdx.x;
    int v = (t < nb) ? btot[t] : 0;
    s[t] = v;
    __syncthreads();
    for (int off = 1; off < 256; off <<= 1) {
        int add = (t >= off) ? s[t - off] : 0;
        __syncthreads();
        s[t] += add;
        __syncthreads();
    }
    Hb[t] = (s[t] - v) + H[blk * 256 + t];   // bucket base + tile offset
    c2[t] = 0;
    __syncthreads();
    int i0 = blk * TILE;
#pragma unroll
    for (int k = 0; k < TILE / 256; ++k) {
        int i = i0 + k * 256 + t;
        if (i < E) {
            int sv = src[i], d = dst[i];
            int b = d >> 8;
            unsigned rec = ((unsigned)(d & 255) << 16) | (unsigned)sv;
            int pos = Hb[b] + atomicAdd(&c2[b], 1);
            tmp[pos] = rec;
        }
    }
}

// ---- L4: per-bucket CSR finalize + P1 rescale + degree-sorted perm ----
__global__ __launch_bounds__(256) void k_binB(const unsigned* __restrict__ tmp,
                                              const int* __restrict__ btot, int nb,
                                              int n, int E, int* __restrict__ row_ptr,
                                              float* __restrict__ inv,
                                              unsigned short* __restrict__ col,
                                              __half* __restrict__ P1,
                                              unsigned short* __restrict__ perm) {
    __shared__ int dcnt[256], s[256], cur[256];
    __shared__ unsigned short colbuf[COLCAP];
    __shared__ int dh[64];
    __shared__ int baseS;
    int t = threadIdx.x, b = blockIdx.x;
    // local scan of btot -> this bucket's base
    int v = (t < nb) ? btot[t] : 0;
    s[t] = v;
    __syncthreads();
    for (int off = 1; off < 256; off <<= 1) {
        int add = (t >= off) ? s[t - off] : 0;
        __syncthreads();
        s[t] += add;
        __syncthreads();
    }
    if (t == b) baseS = s[t] - v;
    dcnt[t] = 0;
    if (t < 64) dh[t] = 0;
    __syncthreads();
    int base = baseS;
    int cntE = btot[b];
    int node0 = b << 8;
    int nn = min(256, n - node0);
    for (int i = t; i < cntE; i += 256) atomicAdd(&dcnt[tmp[base + i] >> 16], 1);
    __syncthreads();
    int deg = dcnt[t];
    s[t] = deg;
    __syncthreads();
    for (int off = 1; off < 256; off <<= 1) {
        int add = (t >= off) ? s[t - off] : 0;
        __syncthreads();
        s[t] += add;
        __syncthreads();
    }
    int excl = s[t] - deg;
    if (t < nn) {
        row_ptr[node0 + t] = base + excl;
        inv[node0 + t] = rsqrtf((float)(deg + 1));
    }
    if (b == 0 && t == 0) row_ptr[n] = E;
    cur[t] = excl;
    __syncthreads();
    for (int i = t; i < cntE; i += 256) {
        unsigned r = tmp[base + i];
        int pos = atomicAdd(&cur[r >> 16], 1);
        unsigned short vv = (unsigned short)(r & 0xFFFFu);
        if (pos < COLCAP) colbuf[pos] = vv;
        else col[base + pos] = vv;   // overflow fallback (never expected at E/n=16)
    }
    __syncthreads();
    int lim = min(cntE, COLCAP);
    for (int i = t; i < lim; i += 256) col[base + i] = colbuf[i];
    // degree-sorted perm within bucket (counting sort, 64 clamped bins)
    int dcl = min(deg, 63);
    if (t < nn) atomicAdd(&dh[dcl], 1);
    __syncthreads();
    if (t == 0) {
        int acc = 0;
#pragma unroll 1
        for (int i = 0; i < 64; ++i) { int x = dh[i]; dh[i] = acc; acc += x; }
    }
    __syncthreads();
    if (t < nn) {
        int rank = atomicAdd(&dh[dcl], 1);   // dh now = running cursor from base
        perm[node0 + rank] = (unsigned short)(node0 + t);
    }
    // rescale this bucket's P1 rows by inv (dcnt still holds deg)
    uint2* P1q = (uint2*)P1;
    for (int i = t; i < nn * 16; i += 256) {
        int r = node0 + (i >> 4);
        int c = i & 15;
        float iv = rsqrtf((float)(dcnt[i >> 4] + 1));
        uint2 q = P1q[(size_t)r * 16 + c];
        float2 f0 = __half22float2(*(__half2*)&q.x);
        float2 f1 = __half22float2(*(__half2*)&q.y);
        __half2 h0 = __floats2half2_rn(f0.x * iv, f0.y * iv);
        __half2 h1 = __floats2half2_rn(f1.x * iv, f1.y * iv);
        P1q[(size_t)r * 16 + c] = make_uint2(*(unsigned*)&h0, *(unsigned*)&h1);
    }
}

// ---- L5: agg layer 1 (via perm) + fused W2 GEMM -> P2 (fp16) ----
__global__ __launch_bounds__(256) void k_aggF1(const __half* __restrict__ Ph, const float* __restrict__ inv,
                                               const int* __restrict__ row_ptr,
                                               const unsigned short* __restrict__ col,
                                               const unsigned short* __restrict__ perm,
                                               const float* __restrict__ bias,
                                               const float* __restrict__ W2,
                                               __half* __restrict__ P2, int n) {
    __shared__ float W2s[FDIM * FDIM];
    __shared__ float rbuf[16][FDIM + 1];
    int t = threadIdx.x;
    for (int i = t; i < FDIM * FDIM; i += 256) W2s[i] = W2[i];
    int lane = t & 63;
    int sub = lane >> 4;
    int fl = lane & 15;
    int wid = t >> 6;
    int nl = wid * 4 + sub;                 // local slot 0..15
    int slot = blockIdx.x * 16 + nl;
    bool alive = slot < n;
    int node = perm[alive ? slot : (n - 1)];
    float iv = inv[node];
    const uint2* Pq = (const uint2*)Ph;
    uint2 selfq = Pq[(size_t)node * 16 + fl];
    float2 sf0 = __half22float2(*(__half2*)&selfq.x);
    float2 sf1 = __half22float2(*(__half2*)&selfq.y);
    float4 acc = make_float4(sf0.x, sf0.y, sf1.x, sf1.y);
    int s = row_ptr[node];
    int e = alive ? row_ptr[node + 1] : s;
    int dmax = e - s;
    dmax = max(dmax, __shfl_xor(dmax, 16, 64));
    dmax = max(dmax, __shfl_xor(dmax, 32, 64));
    for (int j = 0; j < dmax; j += 8) {
        int c[8];
        float wk[8];
        uint2 q[8];
#pragma unroll
        for (int k = 0; k < 8; ++k) {
            int jj = s + j + k;
            bool ok = jj < e;
            c[k] = col[ok ? jj : s];
            wk[k] = ok ? 1.f : 0.f;
        }
#pragma unroll
        for (int k = 0; k < 8; ++k) q[k] = Pq[(size_t)c[k] * 16 + fl];
#pragma unroll
        for (int k = 0; k < 8; ++k) {
            float2 f0 = __half22float2(*(__half2*)&q[k].x);
            float2 f1 = __half22float2(*(__half2*)&q[k].y);
            acc.x = fmaf(wk[k], f0.x, acc.x);
            acc.y = fmaf(wk[k], f0.y, acc.y);
            acc.z = fmaf(wk[k], f1.x, acc.z);
            acc.w = fmaf(wk[k], f1.y, acc.w);
        }
    }
    float4 bb = ((const float4*)bias)[fl];
    rbuf[nl][fl * 4 + 0] = fmaxf(fmaf(iv, acc.x, bb.x), 0.f);
    rbuf[nl][fl * 4 + 1] = fmaxf(fmaf(iv, acc.y, bb.y), 0.f);
    rbuf[nl][fl * 4 + 2] = fmaxf(fmaf(iv, acc.z, bb.z), 0.f);
    rbuf[nl][fl * 4 + 3] = fmaxf(fmaf(iv, acc.w, bb.w), 0.f);
    __syncthreads();   // covers W2s load too
    // Phase B: 256 threads = 16 slots x 16 col-groups
    int nl2 = t >> 4;
    int cg = t & 15;
    int slot2 = blockIdx.x * 16 + nl2;
    const float* rr = rbuf[nl2];
    float a0 = 0.f, a1 = 0.f, a2 = 0.f, a3 = 0.f;
#pragma unroll
    for (int i = 0; i < FDIM; ++i) {
        float xk = rr[i];
        const float* wv = &W2s[i * FDIM + cg * 4];
        a0 = fmaf(xk, wv[0], a0);
        a1 = fmaf(xk, wv[1], a1);
        a2 = fmaf(xk, wv[2], a2);
        a3 = fmaf(xk, wv[3], a3);
    }
    if (slot2 < n) {
        int node2 = perm[slot2];
        float iv2 = inv[node2];
        __half2 h0 = __floats2half2_rn(a0 * iv2, a1 * iv2);
        __half2 h1 = __floats2half2_rn(a2 * iv2, a3 * iv2);
        uint2 val = make_uint2(*(unsigned*)&h0, *(unsigned*)&h1);
        ((uint2*)P2)[(size_t)node2 * 16 + cg] = val;
    }
}

// ---- L6: agg layer 2 (via perm) + fused classifier ----
__global__ __launch_bounds__(256) void k_aggF2(const __half* __restrict__ Ph, const float* __restrict__ inv,
                                               const int* __restrict__ row_ptr,
                                               const unsigned short* __restrict__ col,
                                               const unsigned short* __restrict__ perm,
                                               const float* __restrict__ bias,
                                               const float* __restrict__ Wc, const float* __restrict__ bc,
                                               float* __restrict__ out, int n) {
    __shared__ float WcT[NCLS * FDIM];   // transposed: WcT[c*64+f]
    int t = threadIdx.x;
    for (int i = t; i < FDIM * NCLS; i += 256) {
        int c = i & 15, f = i >> 4;
        WcT[c * FDIM + f] = Wc[i];
    }
    __syncthreads();
    int lane = t & 63;
    int sub = lane >> 4;
    int fl = lane & 15;
    int wid = t >> 6;
    int slot = blockIdx.x * 16 + wid * 4 + sub;
    bool alive = slot < n;
    int node = perm[alive ? slot : (n - 1)];
    float iv = inv[node];
    const uint2* Pq = (const uint2*)Ph;
    uint2 selfq = Pq[(size_t)node * 16 + fl];
    float2 sf0 = __half22float2(*(__half2*)&selfq.x);
    float2 sf1 = __half22float2(*(__half2*)&selfq.y);
    float4 acc = make_float4(sf0.x, sf0.y, sf1.x, sf1.y);
    int s = row_ptr[node];
    int e = alive ? row_ptr[node + 1] : s;
    int dmax = e - s;
    dmax = max(dmax, __shfl_xor(dmax, 16, 64));
    dmax = max(dmax, __shfl_xor(dmax, 32, 64));
    for (int j = 0; j < dmax; j += 8) {
        int c[8];
        float wk[8];
        uint2 q[8];
#pragma unroll
        for (int k = 0; k < 8; ++k) {
            int jj = s + j + k;
            bool ok = jj < e;
            c[k] = col[ok ? jj : s];
            wk[k] = ok ? 1.f : 0.f;
        }
#pragma unroll
        for (int k = 0; k < 8; ++k) q[k] = Pq[(size_t)c[k] * 16 + fl];
#pragma unroll
        for (int k = 0; k < 8; ++k) {
            float2 f0 = __half22float2(*(__half2*)&q[k].x);
            float2 f1 = __half22float2(*(__half2*)&q[k].y);
            acc.x = fmaf(wk[k], f0.x, acc.x);
            acc.y = fmaf(wk[k], f0.y, acc.y);
            acc.z = fmaf(wk[k], f1.x, acc.z);
            acc.w = fmaf(wk[k], f1.y, acc.w);
        }
    }
    float4 bb = ((const float4*)bias)[fl];
    float4 r;
    r.x = fmaxf(fmaf(iv, acc.x, bb.x), 0.f);
    r.y = fmaxf(fmaf(iv, acc.y, bb.y), 0.f);
    r.z = fmaxf(fmaf(iv, acc.z, bb.z), 0.f);
    r.w = fmaxf(fmaf(iv, acc.w, bb.w), 0.f);
    float part[NCLS];
#pragma unroll
    for (int c = 0; c < NCLS; ++c) {
        float4 wv = ((const float4*)(WcT + c * FDIM))[fl];
        part[c] = fmaf(r.x, wv.x, fmaf(r.y, wv.y, fmaf(r.z, wv.z, r.w * wv.w)));
    }
#pragma unroll
    for (int m = 1; m < 16; m <<= 1) {
#pragma unroll
        for (int c = 0; c < NCLS; ++c) part[c] += __shfl_xor(part[c], m, 64);
    }
    if (alive && fl < 4) {
        float4 bb2 = ((const float4*)bc)[fl];
        float4 o = make_float4(part[fl * 4 + 0] + bb2.x, part[fl * 4 + 1] + bb2.y,
                               part[fl * 4 + 2] + bb2.z, part[fl * 4 + 3] + bb2.w);
        ((float4*)out)[(size_t)node * 4 + fl] = o;
    }
}

static inline size_t align256(size_t x) { return (x + 255) & ~(size_t)255; }

extern "C" void kernel_launch(void* const* d_in, const int* in_sizes, int n_in,
                              void* d_out, int out_size, void* d_ws, size_t ws_size,
                              hipStream_t stream) {
    const float* x  = (const float*)d_in[0];
    const int*   ei = (const int*)d_in[1];
    const float* W1 = (const float*)d_in[2];
    const float* b1 = (const float*)d_in[3];
    const float* W2 = (const float*)d_in[4];
    const float* b2 = (const float*)d_in[5];
    const float* Wc = (const float*)d_in[6];
    const float* bc = (const float*)d_in[7];
    float* out = (float*)d_out;

    const int n = in_sizes[0] / FDIM;   // 50000
    const int E = in_sizes[1] / 2;      // 800000
    const int* src = ei;
    const int* dst = ei + E;

    const int nb = (n + 255) >> 8;            // 196 buckets
    const int nblk = (E + TILE - 1) / TILE;   // 391 tiles
    const int nbG = (n * 4 + 255) / 256;      // 782 gemm units
    const int nbA = (n + 15) / 16;            // 3125 agg blocks

    // workspace carve-up
    char* w = (char*)d_ws;
    size_t off = 0;
    int* H = (int*)(w + off);        off = align256(off + (size_t)nblk * 256 * 4);
    int* btot = (int*)(w + off);     off = align256(off + 256 * 4);
    int* row_ptr = (int*)(w + off);  off = align256(off + (size_t)(n + 1) * 4);
    float* inv = (float*)(w + off);  off = align256(off + (size_t)n * 4);
    unsigned* tmp = (unsigned*)(w + off);              off = align256(off + (size_t)E * 4);
    unsigned short* col = (unsigned short*)(w + off);  off = align256(off + (size_t)(E + 8) * 2);
    unsigned short* perm = (unsigned short*)(w + off); off = align256(off + (size_t)n * 2);
    __half* P1 = (__half*)(w + off); off = align256(off + (size_t)n * FDIM * 2);
    __half* P2 = (__half*)(w + off); off = align256(off + (size_t)n * FDIM * 2);
    (void)ws_size;

    // L1: histogram || W1-GEMM (unscaled)
    k_hist_gemm<<<nblk + nbG, 256, 0, stream>>>(dst, E, nblk, H, x, W1, P1, n);
    // L2-L4: CSR finalize chain (+ P1 rescale + degree-sorted perm in binB)
    k_scanH<<<nb, 512, 0, stream>>>(H, nblk, btot);
    k_scatA<<<nblk, 256, 0, stream>>>(src, dst, E, H, btot, nb, tmp);
    k_binB<<<nb, 256, 0, stream>>>(tmp, btot, nb, n, E, row_ptr, inv, col, P1, perm);
    // L5: agg1 + fused W2 GEMM -> P2
    k_aggF1<<<nbA, 256, 0, stream>>>(P1, inv, row_ptr, col, perm, b1, W2, P2, n);
    // L6: agg2 + fused classifier
    k_aggF2<<<nbA, 256, 0, stream>>>(P2, inv, row_ptr, col, perm, b2, Wc, bc, out, n);
}

// Round 13
// 162.041 us; speedup vs baseline: 1.0343x; 1.0343x over previous
//
#include <hip/hip_runtime.h>
#include <hip/hip_fp16.h>

// GCN 2-layer + classifier, fp32 math, fp16 message buffers. (R9 structure — best
// measured config; R11 overlap+rescale and R12 degree-perm both regressed.)
// out[d] = inv[d]*(Ps[d] + sum_{e->d} Ps[src]) + b with Ps = inv*(X@W) (weight-free agg).
// Launches:
//   L1 k_histB: per-tile bucket histogram -> H[tile][bucket]
//   L2 k_scanH: per-bucket exclusive scan of H across tiles + btot
//   L3 k_scatA: scatter {dloc,src} recs into bucket regions (LDS cursors, zero
//               global atomics; R3: coarse global cursors serialize, R6: random
//               scatter = 55MB dirty-line episodes)
//   L4 k_binB:  per-bucket node hist+scan -> row_ptr/inv; coalesced u16 col
//   L5 k_gemm64: P1 = fp16(inv * (x @ W1))  (scaled epilogue)
//   L6 k_aggF1: agg layer1 (masked unroll x12 -> 336 gathers in flight/CU) +
//               fused W2 GEMM via LDS-staged rows (pad 65) -> P2 fp16
//   L7 k_aggF2: agg layer2 (unroll x8) + fused classifier (transposed LDS Wc; R5)
// fp16 message buffers halve gather fetch (R8: 86->45MB, 8-XCD L2 replication).
// R10: hipLaunchCooperativeKernel no-ops under graph capture — do not use.
// n=50000 (<65536 for u16 col), E=800000.

#define FDIM 64
#define NCLS 16
#define TILE 2048
#define COLCAP 8192

// ---- L1: per-(tile,bucket) histogram ----
__global__ __launch_bounds__(256) void k_histB(const int* __restrict__ dst, int E,
                                               int* __restrict__ H) {
    __shared__ int h[256];
    int t = threadIdx.x, blk = blockIdx.x;
    h[t] = 0;
    __syncthreads();
    int i0 = blk * TILE;
#pragma unroll
    for (int k = 0; k < TILE / 256; ++k) {
        int i = i0 + k * 256 + t;
        if (i < E) atomicAdd(&h[dst[i] >> 8], 1);
    }
    __syncthreads();
    H[blk * 256 + t] = h[t];   // coalesced
}

// ---- L2: per-bucket exclusive scan across tiles ----
__global__ __launch_bounds__(512) void k_scanH(int* __restrict__ H, int nblk, int* __restrict__ btot) {
    __shared__ int s[512];
    int t = threadIdx.x, b = blockIdx.x;
    int v = (t < nblk) ? H[t * 256 + b] : 0;
    s[t] = v;
    __syncthreads();
    for (int off = 1; off < 512; off <<= 1) {
        int add = (t >= off) ? s[t - off] : 0;
        __syncthreads();
        s[t] += add;
        __syncthreads();
    }
    if (t < nblk) H[t * 256 + b] = s[t] - v;  // exclusive within bucket
    if (t == 511) btot[b] = s[511];
}

// ---- L3: scatter packed records into bucket regions ----
__global__ __launch_bounds__(256) void k_scatA(const int* __restrict__ src, const int* __restrict__ dst,
                                               int E, const int* __restrict__ H,
                                               const int* __restrict__ btot, int nb,
                                               unsigned* __restrict__ tmp) {
    __shared__ int s[256];
    __shared__ int Hb[256];
    __shared__ int c2[256];
    int t = threadIdx.x, blk = blockIdx.x;
    int v = (t < nb) ? btot[t] : 0;
    s[t] = v;
    __syncthreads();
    for (int off = 1; off < 256; off <<= 1) {
        int add = (t >= off) ? s[t - off] : 0;
        __syncthreads();
        s[t] += add;
        __syncthreads();
    }
    Hb[t] = (s[t] - v) + H[blk * 256 + t];   // bucket base + tile offset
    c2[t] = 0;
    __syncthreads();
    int i0 = blk * TILE;
#pragma unroll
    for (int k = 0; k < TILE / 256; ++k) {
        int i = i0 + k * 256 + t;
        if (i < E) {
            int sv = src[i], d = dst[i];
            int b = d >> 8;
            unsigned rec = ((unsigned)(d & 255) << 16) | (unsigned)sv;
            int pos = Hb[b] + atomicAdd(&c2[b], 1);
            tmp[pos] = rec;
        }
    }
}

// ---- L4: per-bucket CSR finalize ----
__global__ __launch_bounds__(256) void k_binB(const unsigned* __restrict__ tmp,
                                              const int* __restrict__ btot, int nb,
                                              int n, int E, int* __restrict__ row_ptr,
                                              float* __restrict__ inv,
                                              unsigned short* __restrict__ col) {
    __shared__ int dcnt[256], s[256], cur[256];
    __shared__ unsigned short colbuf[COLCAP];
    __shared__ int baseS;
    int t = threadIdx.x, b = blockIdx.x;
    // local scan of btot -> this bucket's base
    int v = (t < nb) ? btot[t] : 0;
    s[t] = v;
    __syncthreads();
    for (int off = 1; off < 256; off <<= 1) {
        int add = (t >= off) ? s[t - off] : 0;
        __syncthreads();
        s[t] += add;
        __syncthreads();
    }
    if (t == b) baseS = s[t] - v;
    dcnt[t] = 0;
    __syncthreads();
    int base = baseS;
    int cntE = btot[b];
    int node0 = b << 8;
    int nn = min(256, n - node0);
    for (int i = t; i < cntE; i += 256) atomicAdd(&dcnt[tmp[base + i] >> 16], 1);
    __syncthreads();
    int deg = dcnt[t];
    s[t] = deg;
    __syncthreads();
    for (int off = 1; off < 256; off <<= 1) {
        int add = (t >= off) ? s[t - off] : 0;
        __syncthreads();
        s[t] += add;
        __syncthreads();
    }
    int excl = s[t] - deg;
    if (t < nn) {
        row_ptr[node0 + t] = base + excl;
        inv[node0 + t] = rsqrtf((float)(deg + 1));
    }
    if (b == 0 && t == 0) row_ptr[n] = E;
    cur[t] = excl;
    __syncthreads();
    for (int i = t; i < cntE; i += 256) {
        unsigned r = tmp[base + i];
        int pos = atomicAdd(&cur[r >> 16], 1);
        unsigned short vv = (unsigned short)(r & 0xFFFFu);
        if (pos < COLCAP) colbuf[pos] = vv;
        else col[base + pos] = vv;   // overflow fallback (never expected at E/n=16)
    }
    __syncthreads();
    int lim = min(cntE, COLCAP);
    for (int i = t; i < lim; i += 256) col[base + i] = colbuf[i];
}

// ---- L5: P1[row] = fp16( inv[row] * (X[row] @ W) ) ----
__global__ __launch_bounds__(256) void k_gemm64(const float* __restrict__ X, const float* __restrict__ W,
                                                const float* __restrict__ inv, __half* __restrict__ Yh, int n) {
    __shared__ float Ws[FDIM * FDIM];
    int t = threadIdx.x;
    for (int i = t; i < FDIM * FDIM; i += 256) Ws[i] = W[i];
    __syncthreads();
    int idx = blockIdx.x * 256 + t;
    int row = idx >> 2;
    int cg = (idx & 3) * 16;
    if (row >= n) return;
    const float4* xr = (const float4*)(X + (size_t)row * FDIM);
    float4 xv[16];
#pragma unroll
    for (int i = 0; i < 16; ++i) xv[i] = xr[i];
    float acc[16];
#pragma unroll
    for (int c = 0; c < 16; ++c) acc[c] = 0.f;
#pragma unroll
    for (int i = 0; i < 16; ++i) {
        float xs[4] = {xv[i].x, xv[i].y, xv[i].z, xv[i].w};
#pragma unroll
        for (int j = 0; j < 4; ++j) {
            float xk = xs[j];
            const float* wr = &Ws[(i * 4 + j) * FDIM + cg];
#pragma unroll
            for (int c = 0; c < 16; ++c) acc[c] += xk * wr[c];
        }
    }
    float iv = inv[row];
    unsigned u[8];
#pragma unroll
    for (int i = 0; i < 8; ++i) {
        __half2 hp = __floats2half2_rn(acc[2 * i] * iv, acc[2 * i + 1] * iv);
        u[i] = *(unsigned*)&hp;
    }
    uint4* yo = (uint4*)(Yh + (size_t)row * FDIM + cg);
    yo[0] = make_uint4(u[0], u[1], u[2], u[3]);
    yo[1] = make_uint4(u[4], u[5], u[6], u[7]);
}

// ---- L6: agg layer 1 (masked unroll x12) + fused W2 GEMM -> P2 (fp16) ----
__global__ __launch_bounds__(256) void k_aggF1(const __half* __restrict__ Ph, const float* __restrict__ inv,
                                               const int* __restrict__ row_ptr,
                                               const unsigned short* __restrict__ col,
                                               const float* __restrict__ bias,
                                               const float* __restrict__ W2,
                                               __half* __restrict__ P2, int n) {
    __shared__ float W2s[FDIM * FDIM];
    __shared__ float rbuf[16][FDIM + 1];
    int t = threadIdx.x;
    for (int i = t; i < FDIM * FDIM; i += 256) W2s[i] = W2[i];
    int lane = t & 63;
    int sub = lane >> 4;
    int fl = lane & 15;
    int wid = t >> 6;
    int nl = wid * 4 + sub;                 // local node 0..15
    int node = blockIdx.x * 16 + nl;
    bool alive = node < n;
    int nodeC = alive ? node : (n - 1);
    float iv = inv[nodeC];
    const uint2* Pq = (const uint2*)Ph;
    uint2 selfq = Pq[(size_t)nodeC * 16 + fl];
    float2 sf0 = __half22float2(*(__half2*)&selfq.x);
    float2 sf1 = __half22float2(*(__half2*)&selfq.y);
    float4 acc = make_float4(sf0.x, sf0.y, sf1.x, sf1.y);
    int s = row_ptr[nodeC];
    int e = alive ? row_ptr[nodeC + 1] : s;
    int dmax = e - s;
    dmax = max(dmax, __shfl_xor(dmax, 16, 64));
    dmax = max(dmax, __shfl_xor(dmax, 32, 64));
    // masked unroll x12: 12 independent gathers per wave-quad slot in flight
    for (int j = 0; j < dmax; j += 12) {
        int c[12];
        float wk[12];
        uint2 q[12];
#pragma unroll
        for (int k = 0; k < 12; ++k) {
            int jj = s + j + k;
            bool ok = jj < e;
            c[k] = col[ok ? jj : s];
            wk[k] = ok ? 1.f : 0.f;
        }
#pragma unroll
        for (int k = 0; k < 12; ++k) q[k] = Pq[(size_t)c[k] * 16 + fl];
#pragma unroll
        for (int k = 0; k < 12; ++k) {
            float2 f0 = __half22float2(*(__half2*)&q[k].x);
            float2 f1 = __half22float2(*(__half2*)&q[k].y);
            acc.x = fmaf(wk[k], f0.x, acc.x);
            acc.y = fmaf(wk[k], f0.y, acc.y);
            acc.z = fmaf(wk[k], f1.x, acc.z);
            acc.w = fmaf(wk[k], f1.y, acc.w);
        }
    }
    float4 bb = ((const float4*)bias)[fl];
    rbuf[nl][fl * 4 + 0] = fmaxf(fmaf(iv, acc.x, bb.x), 0.f);
    rbuf[nl][fl * 4 + 1] = fmaxf(fmaf(iv, acc.y, bb.y), 0.f);
    rbuf[nl][fl * 4 + 2] = fmaxf(fmaf(iv, acc.z, bb.z), 0.f);
    rbuf[nl][fl * 4 + 3] = fmaxf(fmaf(iv, acc.w, bb.w), 0.f);
    __syncthreads();   // covers W2s load too
    // Phase B: 256 threads = 16 nodes x 16 col-groups
    int nl2 = t >> 4;
    int cg = t & 15;
    int node2 = blockIdx.x * 16 + nl2;
    const float* rr = rbuf[nl2];
    float a0 = 0.f, a1 = 0.f, a2 = 0.f, a3 = 0.f;
#pragma unroll
    for (int i = 0; i < FDIM; ++i) {
        float xk = rr[i];
        const float* wv = &W2s[i * FDIM + cg * 4];
        a0 = fmaf(xk, wv[0], a0);
        a1 = fmaf(xk, wv[1], a1);
        a2 = fmaf(xk, wv[2], a2);
        a3 = fmaf(xk, wv[3], a3);
    }
    if (node2 < n) {
        float iv2 = inv[node2];
        __half2 h0 = __floats2half2_rn(a0 * iv2, a1 * iv2);
        __half2 h1 = __floats2half2_rn(a2 * iv2, a3 * iv2);
        uint2 val = make_uint2(*(unsigned*)&h0, *(unsigned*)&h1);
        ((uint2*)P2)[(size_t)node2 * 16 + cg] = val;
    }
}

// ---- L7: agg layer 2 (unroll x8) + fused classifier ----
__global__ __launch_bounds__(256) void k_aggF2(const __half* __restrict__ Ph, const float* __restrict__ inv,
                                               const int* __restrict__ row_ptr,
                                               const unsigned short* __restrict__ col,
                                               const float* __restrict__ bias,
                                               const float* __restrict__ Wc, const float* __restrict__ bc,
                                               float* __restrict__ out, int n) {
    __shared__ float WcT[NCLS * FDIM];   // transposed: WcT[c*64+f]
    int t = threadIdx.x;
    for (int i = t; i < FDIM * NCLS; i += 256) {
        int c = i & 15, f = i >> 4;
        WcT[c * FDIM + f] = Wc[i];
    }
    __syncthreads();
    int lane = t & 63;
    int sub = lane >> 4;
    int fl = lane & 15;
    int wid = t >> 6;
    int node = blockIdx.x * 16 + wid * 4 + sub;
    bool alive = node < n;
    int nodeC = alive ? node : (n - 1);
    float iv = inv[nodeC];
    const uint2* Pq = (const uint2*)Ph;
    uint2 selfq = Pq[(size_t)nodeC * 16 + fl];
    float2 sf0 = __half22float2(*(__half2*)&selfq.x);
    float2 sf1 = __half22float2(*(__half2*)&selfq.y);
    float4 acc = make_float4(sf0.x, sf0.y, sf1.x, sf1.y);
    int s = row_ptr[nodeC];
    int e = alive ? row_ptr[nodeC + 1] : s;
    int dmax = e - s;
    dmax = max(dmax, __shfl_xor(dmax, 16, 64));
    dmax = max(dmax, __shfl_xor(dmax, 32, 64));
    for (int j = 0; j < dmax; j += 8) {
        int c[8];
        float wk[8];
        uint2 q[8];
#pragma unroll
        for (int k = 0; k < 8; ++k) {
            int jj = s + j + k;
            bool ok = jj < e;
            c[k] = col[ok ? jj : s];
            wk[k] = ok ? 1.f : 0.f;
        }
#pragma unroll
        for (int k = 0; k < 8; ++k) q[k] = Pq[(size_t)c[k] * 16 + fl];
#pragma unroll
        for (int k = 0; k < 8; ++k) {
            float2 f0 = __half22float2(*(__half2*)&q[k].x);
            float2 f1 = __half22float2(*(__half2*)&q[k].y);
            acc.x = fmaf(wk[k], f0.x, acc.x);
            acc.y = fmaf(wk[k], f0.y, acc.y);
            acc.z = fmaf(wk[k], f1.x, acc.z);
            acc.w = fmaf(wk[k], f1.y, acc.w);
        }
    }
    float4 bb = ((const float4*)bias)[fl];
    float4 r;
    r.x = fmaxf(fmaf(iv, acc.x, bb.x), 0.f);
    r.y = fmaxf(fmaf(iv, acc.y, bb.y), 0.f);
    r.z = fmaxf(fmaf(iv, acc.z, bb.z), 0.f);
    r.w = fmaxf(fmaf(iv, acc.w, bb.w), 0.f);
    float part[NCLS];
#pragma unroll
    for (int c = 0; c < NCLS; ++c) {
        float4 wv = ((const float4*)(WcT + c * FDIM))[fl];
        part[c] = fmaf(r.x, wv.x, fmaf(r.y, wv.y, fmaf(r.z, wv.z, r.w * wv.w)));
    }
#pragma unroll
    for (int m = 1; m < 16; m <<= 1) {
#pragma unroll
        for (int c = 0; c < NCLS; ++c) part[c] += __shfl_xor(part[c], m, 64);
    }
    if (alive && fl < 4) {
        float4 bb2 = ((const float4*)bc)[fl];
        float4 o = make_float4(part[fl * 4 + 0] + bb2.x, part[fl * 4 + 1] + bb2.y,
                               part[fl * 4 + 2] + bb2.z, part[fl * 4 + 3] + bb2.w);
        ((float4*)out)[(size_t)node * 4 + fl] = o;
    }
}

static inline size_t align256(size_t x) { return (x + 255) & ~(size_t)255; }

extern "C" void kernel_launch(void* const* d_in, const int* in_sizes, int n_in,
                              void* d_out, int out_size, void* d_ws, size_t ws_size,
                              hipStream_t stream) {
    const float* x  = (const float*)d_in[0];
    const int*   ei = (const int*)d_in[1];
    const float* W1 = (const float*)d_in[2];
    const float* b1 = (const float*)d_in[3];
    const float* W2 = (const float*)d_in[4];
    const float* b2 = (const float*)d_in[5];
    const float* Wc = (const float*)d_in[6];
    const float* bc = (const float*)d_in[7];
    float* out = (float*)d_out;

    const int n = in_sizes[0] / FDIM;   // 50000
    const int E = in_sizes[1] / 2;      // 800000
    const int* src = ei;
    const int* dst = ei + E;

    const int nb = (n + 255) >> 8;            // 196 buckets
    const int nblk = (E + TILE - 1) / TILE;   // 391 tiles
    const int nbG = (n * 4 + 255) / 256;      // 782 gemm units
    const int nbA = (n + 15) / 16;            // 3125 agg blocks

    // workspace carve-up
    char* w = (char*)d_ws;
    size_t off = 0;
    int* H = (int*)(w + off);        off = align256(off + (size_t)nblk * 256 * 4);
    int* btot = (int*)(w + off);     off = align256(off + 256 * 4);
    int* row_ptr = (int*)(w + off);  off = align256(off + (size_t)(n + 1) * 4);
    float* inv = (float*)(w + off);  off = align256(off + (size_t)n * 4);
    unsigned* tmp = (unsigned*)(w + off);             off = align256(off + (size_t)E * 4);
    unsigned short* col = (unsigned short*)(w + off); off = align256(off + (size_t)(E + 16) * 2);
    __half* P1 = (__half*)(w + off); off = align256(off + (size_t)n * FDIM * 2);
    __half* P2 = (__half*)(w + off); off = align256(off + (size_t)n * FDIM * 2);
    (void)ws_size;

    // CSR build: radix partition, zero global atomics
    k_histB<<<nblk, 256, 0, stream>>>(dst, E, H);
    k_scanH<<<nb, 512, 0, stream>>>(H, nblk, btot);
    k_scatA<<<nblk, 256, 0, stream>>>(src, dst, E, H, btot, nb, tmp);
    k_binB<<<nb, 256, 0, stream>>>(tmp, btot, nb, n, E, row_ptr, inv, col);

    // layer 1 GEMM (scaled, fp16 out)
    k_gemm64<<<nbG, 256, 0, stream>>>(x, W1, inv, P1, n);
    // layer 1 agg + fused W2 GEMM -> P2
    k_aggF1<<<nbA, 256, 0, stream>>>(P1, inv, row_ptr, col, b1, W2, P2, n);
    // layer 2 agg + fused classifier
    k_aggF2<<<nbA, 256, 0, stream>>>(P2, inv, row_ptr, col, b2, Wc, bc, out, n);
}